// Round 6
// baseline (256.583 us; speedup 1.0000x reference)
//
#include <hip/hip_runtime.h>
#include <stdint.h>

// DepthAttentionResidual: S=16, B=4, T=1024, D=2048, fp32 in/out.
// Register-resident, fp16-packed mix operands, 3 blocks/CU.
//   - one block (512 thr) per (b,t); thread tid owns float4 d-slice `tid`
//   - scores (p2 = sum x^2, pq = sum q.x) computed in fp32 from the loaded
//     values BEFORE packing -> score path is fp32-exact
//   - mix operands kept as fp16x4 in registers (32 VGPR instead of 64)
//   - __launch_bounds__(512,6) -> <=85 VGPR -> 3 blocks/CU, LDS ~1KB
//   - nontemporal loads/stores: bank & out have zero reuse
//   - loads issued in 4 batches of 4 to bound transient VGPR pressure

#define NSRC 16
#define NB   4
#define NT   1024
#define ND   2048

typedef float  f32x4 __attribute__((ext_vector_type(4)));
typedef __fp16 h16x2 __attribute__((ext_vector_type(2)));

__global__ __launch_bounds__(512, 6)
void dar_reg16_kernel(const float* __restrict__ q,
                      const float* __restrict__ bank,
                      float* __restrict__ out) {
    __shared__ float2 red[8][NSRC];   // per-wave (p2,pq) partials, 1 KB

    const int tid  = threadIdx.x;     // 0..511
    const int wave = tid >> 6;        // 0..7
    const int lane = tid & 63;
    const int bt   = blockIdx.x;      // b*NT + t

    const f32x4* bt_base = reinterpret_cast<const f32x4*>(bank)
                         + (size_t)bt * (ND / 4) + tid;
    const f32x4 qv = reinterpret_cast<const f32x4*>(q)[tid];  // L2-hot, normal load

    const size_t SSTRIDE = (size_t)(NB * NT) * (ND / 4);      // f32x4 units per source

    uint2 xh[NSRC];            // fp16x4-packed mix operands (32 VGPR)
    float p2[NSRC], pq[NSRC];

    // ---- Load + score-partials + pack, 4 sources per batch ----
    #pragma unroll
    for (int g = 0; g < 4; ++g) {
        f32x4 v[4];
        #pragma unroll
        for (int k = 0; k < 4; ++k)
            v[k] = __builtin_nontemporal_load(bt_base + (size_t)(g * 4 + k) * SSTRIDE);
        #pragma unroll
        for (int k = 0; k < 4; ++k) {
            const int s = g * 4 + k;
            p2[s] = v[k].x * v[k].x + v[k].y * v[k].y + v[k].z * v[k].z + v[k].w * v[k].w;
            pq[s] = qv.x * v[k].x + qv.y * v[k].y + qv.z * v[k].z + qv.w * v[k].w;
            const h16x2 lo = __builtin_amdgcn_cvt_pkrtz(v[k].x, v[k].y);
            const h16x2 hi = __builtin_amdgcn_cvt_pkrtz(v[k].z, v[k].w);
            xh[s].x = __builtin_bit_cast(uint32_t, lo);
            xh[s].y = __builtin_bit_cast(uint32_t, hi);
        }
    }

    // ---- 64-lane butterflies (independent across sources -> good ILP) ----
    #pragma unroll
    for (int s = 0; s < NSRC; ++s) {
        #pragma unroll
        for (int m = 32; m >= 1; m >>= 1) {
            p2[s] += __shfl_xor(p2[s], m, 64);
            pq[s] += __shfl_xor(pq[s], m, 64);
        }
    }
    if (lane == 0) {
        #pragma unroll
        for (int s = 0; s < NSRC; ++s)
            red[wave][s] = make_float2(p2[s], pq[s]);
    }
    __syncthreads();

    // ---- Final reduce: lane l handles source l&15 (lanes 16+ broadcast-read) ----
    const int sl = lane & 15;
    float tp2 = 0.0f, tpq = 0.0f;
    #pragma unroll
    for (int w = 0; w < 8; ++w) {
        const float2 r = red[w][sl];
        tp2 += r.x;
        tpq += r.y;
    }
    const float score = tpq * rsqrtf(tp2 * (1.0f / ND) + 1.1920928955078125e-07f)
                      * 0.022097086912079608f;   // 1/sqrt(2048)

    // ---- Softmax over the 16-lane group ----
    float mx = score;
    #pragma unroll
    for (int m = 1; m <= 8; m <<= 1) mx = fmaxf(mx, __shfl_xor(mx, m, 64));
    const float es = __expf(score - mx);
    float sum = es;
    #pragma unroll
    for (int m = 1; m <= 8; m <<= 1) sum += __shfl_xor(sum, m, 64);
    const float esn = es / sum;   // normalized weight for source lane&15

    // ---- Mix from fp16-packed registers; weights broadcast from lanes 0..15 ----
    float ax = 0.0f, ay = 0.0f, az = 0.0f, aw = 0.0f;
    #pragma unroll
    for (int s = 0; s < NSRC; ++s) {
        const float ws = __shfl(esn, s, 64);
        const h16x2 lo = __builtin_bit_cast(h16x2, xh[s].x);
        const h16x2 hi = __builtin_bit_cast(h16x2, xh[s].y);
        ax += ws * (float)lo.x;
        ay += ws * (float)lo.y;
        az += ws * (float)hi.x;
        aw += ws * (float)hi.y;
    }
    f32x4 r;
    r.x = ax; r.y = ay; r.z = az; r.w = aw;
    __builtin_nontemporal_store(r, reinterpret_cast<f32x4*>(out) + (size_t)bt * (ND / 4) + tid);
}

extern "C" void kernel_launch(void* const* d_in, const int* in_sizes, int n_in,
                              void* d_out, int out_size, void* d_ws, size_t ws_size,
                              hipStream_t stream) {
    const float* q    = (const float*)d_in[0];   // [D] fp32
    const float* bank = (const float*)d_in[1];   // [S,B,T,D] fp32
    float* out        = (float*)d_out;           // [B,T,D] fp32

    dim3 grid(NB * NT);
    dim3 block(512);
    dar_reg16_kernel<<<grid, block, 0, stream>>>(q, bank, out);
}

// Round 7
// 236.460 us; speedup vs baseline: 1.0851x; 1.0851x over previous
//
#include <hip/hip_runtime.h>
#include <stdint.h>

// DepthAttentionResidual: S=16, B=4, T=1024, D=2048, fp32 in/out.
// Persistent pipelined family-A:
//   512 blocks x 1024 thr (16 waves, wave = source), 8 tiles per block.
//   2 blocks/CU requires VGPR <= 64 (m69 cliff) -> launch_bounds(1024,8):
//     single reg landing set v[8] (32 VGPR), q reloaded per tile (L1-hot),
//     softmax recomputed per thread, fp16 single-buffer LDS tile (64 KB).
//   Per tile: wait loads(t) -> p2/pq -> butterfly -> [barrier A] -> fp16
//   pack + ds_write + score -> lgkmcnt(0) -> [barrier B] -> issue loads(t+1)
//   -> softmax -> mix from LDS -> store. Prefetch is consumed before the
//   next barrier A, so it never crosses a barrier (no vmcnt-drain trap);
//   raw s_barrier (not __syncthreads) avoids store/load drains.

#define NSRC  16
#define NB    4
#define NT    1024
#define ND    2048
#define TILES 8
#define NBLK  512   // (NB*NT)/TILES

typedef __fp16 h16x2 __attribute__((ext_vector_type(2)));
typedef float  f32x4 __attribute__((ext_vector_type(4)));

__global__ __launch_bounds__(1024, 8)   // cap 64 VGPR -> 32 waves/CU
void dar_pipe_kernel(const float* __restrict__ q,
                     const float* __restrict__ bank,
                     float* __restrict__ out) {
    __shared__ uint32_t buf[NSRC][ND / 2];  // fp16x2 tile, 64 KB, single buffer
    __shared__ float s_sc[NSRC];

    const int tid  = threadIdx.x;
    const int wave = tid >> 6;      // source index
    const int lane = tid & 63;
    const int bt0  = blockIdx.x * TILES;

    const f32x4* srcbase = reinterpret_cast<const f32x4*>(bank)
                         + ((size_t)wave * (NB * NT) + bt0) * (ND / 4);
    const f32x4* q4 = reinterpret_cast<const f32x4*>(q);

    f32x4 v[8];                      // single landing set, reused across tiles
    #pragma unroll
    for (int i = 0; i < 8; ++i) v[i] = srcbase[i * 64 + lane];   // tile 0

    for (int t = 0; t < TILES; ++t) {
        // ---- scores from v (load wait lives here; HBM busy on our stream) ----
        float p2 = 0.0f, pq = 0.0f;
        #pragma unroll
        for (int i = 0; i < 8; ++i) {
            const f32x4 qv = q4[i * 64 + lane];   // L1-hot reload (keeps VGPR low)
            const f32x4 x  = v[i];
            p2 += x.x * x.x + x.y * x.y + x.z * x.z + x.w * x.w;
            pq += qv.x * x.x + qv.y * x.y + qv.z * x.z + qv.w * x.w;
        }
        #pragma unroll
        for (int m = 32; m >= 1; m >>= 1) {
            p2 += __shfl_xor(p2, m, 64);
            pq += __shfl_xor(pq, m, 64);
        }

        // ---- barrier A: all waves finished reading buf for tile t-1 ----
        __builtin_amdgcn_s_barrier();

        // ---- stage tile t as fp16 (frees v for the prefetch) + score ----
        #pragma unroll
        for (int i = 0; i < 8; ++i) {
            const h16x2 lo = __builtin_amdgcn_cvt_pkrtz(v[i].x, v[i].y);
            const h16x2 hi = __builtin_amdgcn_cvt_pkrtz(v[i].z, v[i].w);
            uint2 u;
            u.x = __builtin_bit_cast(uint32_t, lo);
            u.y = __builtin_bit_cast(uint32_t, hi);
            reinterpret_cast<uint2*>(&buf[wave][0])[i * 64 + lane] = u;
        }
        if (lane == 0) {
            s_sc[wave] = pq * rsqrtf(p2 * (1.0f / ND) + 1.1920928955078125e-07f)
                       * 0.022097086912079608f;   // 1/sqrt(2048)
        }
        asm volatile("s_waitcnt lgkmcnt(0)" ::: "memory");  // writes visible
        __builtin_amdgcn_s_barrier();                       // barrier B: staged

        // ---- prefetch tile t+1 (in flight under softmax+mix+store) ----
        if (t + 1 < TILES) {
            const f32x4* s2 = srcbase + (size_t)(t + 1) * (ND / 4);
            #pragma unroll
            for (int i = 0; i < 8; ++i) v[i] = s2[i * 64 + lane];
        }

        // ---- softmax over 16 scores (redundant per thread) ----
        float sc[NSRC];
        float mx = -1e30f;
        #pragma unroll
        for (int s = 0; s < NSRC; ++s) { sc[s] = s_sc[s]; mx = fmaxf(mx, sc[s]); }
        float sum = 0.0f;
        #pragma unroll
        for (int s = 0; s < NSRC; ++s) { sc[s] = __expf(sc[s] - mx); sum += sc[s]; }
        const float inv = 1.0f / sum;

        // ---- mix: thread owns half2 column tid (2-way bank alias = free) ----
        float ax = 0.0f, ay = 0.0f;
        #pragma unroll
        for (int s = 0; s < NSRC; ++s) {
            const h16x2 h = __builtin_bit_cast(h16x2, buf[s][tid]);
            const float w = sc[s] * inv;
            ax += w * (float)h.x;
            ay += w * (float)h.y;
        }
        float2 r;
        r.x = ax;
        r.y = ay;
        reinterpret_cast<float2*>(out + (size_t)(bt0 + t) * ND)[tid] = r;
    }
}

extern "C" void kernel_launch(void* const* d_in, const int* in_sizes, int n_in,
                              void* d_out, int out_size, void* d_ws, size_t ws_size,
                              hipStream_t stream) {
    const float* q    = (const float*)d_in[0];   // [D] fp32
    const float* bank = (const float*)d_in[1];   // [S,B,T,D] fp32
    float* out        = (float*)d_out;           // [B,T,D] fp32

    dim3 grid(NBLK);
    dim3 block(1024);
    dar_pipe_kernel<<<grid, block, 0, stream>>>(q, bank, out);
}

// Round 8
// 201.420 us; speedup vs baseline: 1.2739x; 1.1740x over previous
//
#include <hip/hip_runtime.h>
#include <stdint.h>

// DepthAttentionResidual: S=16, B=4, T=1024, D=2048, fp32 in/out.
// Register-resident, fp16-packed mix operands, 512-thr blocks, 4 tiles/block.
//   - thread tid owns f32x4 d-slice `tid` (512*4 = 2048 = D) for one (b,t)
//   - per tile: 4 groups of 4 sources -> load f32x4, fp32 score partials,
//     64-lane butterfly IMMEDIATELY (no p2/pq arrays), pack value to fp16
//   - per-wave partials in tiny LDS (red, 2 KB, tile-parity double-buffered)
//   - raw s_barrier + lgkmcnt(0) (no vmcnt drain) so the next tile's first
//     group, prefetched during group 3, stays in flight across the barrier
//   - softmax over 16 lanes via shfl_xor; weights broadcast via __shfl
//   - mix from fp16 regs (score path fp32-exact; mix err ~1e-2 << 6.3e-2)
// VGPR budget: xh 32 + v 16 + qv 4 + misc ~20 = ~72 <= 85 cap (512,6)
//   -> 3 blocks/CU = 24 waves/CU. 512-thr granularity degrades gracefully.

#define NSRC  16
#define NB    4
#define NT    1024
#define ND    2048
#define TILES 4
#define NBLK  ((NB * NT) / TILES)   // 1024

typedef float  f32x4 __attribute__((ext_vector_type(4)));
typedef __fp16 h16x2 __attribute__((ext_vector_type(2)));

__global__ __launch_bounds__(512, 6)
void dar_reg_pipe_kernel(const float* __restrict__ q,
                         const float* __restrict__ bank,
                         float* __restrict__ out) {
    __shared__ float2 red[2][8][NSRC];   // [tile parity][wave][source], 2 KB

    const int tid  = threadIdx.x;        // 0..511
    const int wave = tid >> 6;           // 0..7
    const int lane = tid & 63;
    const int sl   = lane & 15;          // source handled by this lane post-reduce
    const int bt0  = blockIdx.x * TILES;

    const f32x4  qv  = reinterpret_cast<const f32x4*>(q)[tid];
    const size_t SST = (size_t)(NB * NT) * (ND / 4);   // source stride, f32x4 units
    const f32x4* base = reinterpret_cast<const f32x4*>(bank)
                      + (size_t)bt0 * (ND / 4) + tid;

    // Preload tile 0, group 0 (sources 0..3).
    f32x4 v[4];
    #pragma unroll
    for (int k = 0; k < 4; ++k) v[k] = base[(size_t)k * SST];

    for (int t = 0; t < TILES; ++t) {
        const int par = t & 1;
        uint2 xh[NSRC];                  // fp16x4-packed mix operands

        #pragma unroll
        for (int g = 0; g < 4; ++g) {
            // ---- compute group g (sources 4g..4g+3) from v ----
            #pragma unroll
            for (int k = 0; k < 4; ++k) {
                const int s = g * 4 + k;
                const f32x4 x = v[k];
                float p2 = x.x * x.x + x.y * x.y + x.z * x.z + x.w * x.w;
                float pq = qv.x * x.x + qv.y * x.y + qv.z * x.z + qv.w * x.w;
                #pragma unroll
                for (int m = 32; m >= 1; m >>= 1) {
                    p2 += __shfl_xor(p2, m, 64);
                    pq += __shfl_xor(pq, m, 64);
                }
                if (lane == 0) red[par][wave][s] = make_float2(p2, pq);
                const h16x2 lo = __builtin_amdgcn_cvt_pkrtz(x.x, x.y);
                const h16x2 hi = __builtin_amdgcn_cvt_pkrtz(x.z, x.w);
                xh[s].x = __builtin_bit_cast(uint32_t, lo);
                xh[s].y = __builtin_bit_cast(uint32_t, hi);
            }
            // ---- refill v: next group, or next tile's group 0 ----
            if (g < 3) {
                const f32x4* p = base + (size_t)t * (ND / 4);
                #pragma unroll
                for (int k = 0; k < 4; ++k)
                    v[k] = p[(size_t)((g + 1) * 4 + k) * SST];
            } else if (t + 1 < TILES) {
                const f32x4* p = base + (size_t)(t + 1) * (ND / 4);
                #pragma unroll
                for (int k = 0; k < 4; ++k)
                    v[k] = p[(size_t)k * SST];
            }
        }

        // ---- raw barrier: drain LDS writes only (prefetch stays in flight) ----
        asm volatile("s_waitcnt lgkmcnt(0)" ::: "memory");
        __builtin_amdgcn_s_barrier();

        // ---- final reduce for source sl across the 8 waves ----
        float tp2 = 0.0f, tpq = 0.0f;
        #pragma unroll
        for (int w = 0; w < 8; ++w) {
            const float2 r = red[par][w][sl];
            tp2 += r.x;
            tpq += r.y;
        }
        const float score = tpq * rsqrtf(tp2 * (1.0f / ND) + 1.1920928955078125e-07f)
                          * 0.022097086912079608f;   // 1/sqrt(2048)

        // ---- softmax within the 16-lane group ----
        float mx = score;
        #pragma unroll
        for (int m = 1; m <= 8; m <<= 1) mx = fmaxf(mx, __shfl_xor(mx, m, 64));
        const float es = __expf(score - mx);
        float sum = es;
        #pragma unroll
        for (int m = 1; m <= 8; m <<= 1) sum += __shfl_xor(sum, m, 64);
        const float esn = es / sum;

        // ---- mix from fp16 regs; weights broadcast from lanes 0..15 ----
        float ax = 0.0f, ay = 0.0f, az = 0.0f, aw = 0.0f;
        #pragma unroll
        for (int s = 0; s < NSRC; ++s) {
            const float ws = __shfl(esn, s, 64);
            const h16x2 lo = __builtin_bit_cast(h16x2, xh[s].x);
            const h16x2 hi = __builtin_bit_cast(h16x2, xh[s].y);
            ax += ws * (float)lo.x;
            ay += ws * (float)lo.y;
            az += ws * (float)hi.x;
            aw += ws * (float)hi.y;
        }
        f32x4 r;
        r.x = ax; r.y = ay; r.z = az; r.w = aw;
        reinterpret_cast<f32x4*>(out)[(size_t)(bt0 + t) * (ND / 4) + tid] = r;
    }
}

extern "C" void kernel_launch(void* const* d_in, const int* in_sizes, int n_in,
                              void* d_out, int out_size, void* d_ws, size_t ws_size,
                              hipStream_t stream) {
    const float* q    = (const float*)d_in[0];   // [D] fp32
    const float* bank = (const float*)d_in[1];   // [S,B,T,D] fp32
    float* out        = (float*)d_out;           // [B,T,D] fp32

    dim3 grid(NBLK);
    dim3 block(512);
    dar_reg_pipe_kernel<<<grid, block, 0, stream>>>(q, bank, out);
}

// Round 10
// 98.122 us; speedup vs baseline: 2.6149x; 2.0527x over previous
//
#include <hip/hip_runtime.h>

// DepthAttentionResidual: S=16 sources, B=4, T=1024, D=2048, fp32 in/out.
// R3 structure (proven 111 us, 2 blocks/CU, 32 waves/CU) + zero-VGPR-cost
// micro-opts:
//   - nontemporal loads for bank (512 MB streamed once, no reuse)
//   - nontemporal store for out (write-once)
//   - raw s_barrier with lgkmcnt(0)-only drain instead of __syncthreads()
//     (avoids the vmcnt(0) drain; global loads are consumed via use-waits
//     before the barrier, only ds_write visibility is required)
// NOTE: nontemporal builtins require ext_vector types, not HIP_vector_type.

#define NSRC 16
#define NB   4
#define NT   1024
#define ND   2048

typedef __fp16 half2_t __attribute__((ext_vector_type(2)));
typedef float  f32x4   __attribute__((ext_vector_type(4)));
typedef float  f32x2   __attribute__((ext_vector_type(2)));

__global__ __launch_bounds__(1024, 8)
void dar_fused_kernel(const float* __restrict__ q,
                      const float* __restrict__ bank,
                      float* __restrict__ out) {
    __shared__ half2_t lds[NSRC * (ND / 2)];   // 64 KB
    __shared__ float s_scores[NSRC];

    const int bt   = blockIdx.x;       // b*NT + t
    const int tid  = threadIdx.x;      // 0..1023
    const int wave = tid >> 6;         // 0..15 == source index
    const int lane = tid & 63;

    // ---- Stage source `wave` into LDS (fp16); fuse sum(x^2), sum(q*x) ----
    const f32x4* src = reinterpret_cast<const f32x4*>(
        bank + ((size_t)wave * NB * NT + bt) * ND);
    const f32x4* q4  = reinterpret_cast<const f32x4*>(q);
    half2_t* ldsrow  = lds + wave * (ND / 2);

    float p2 = 0.0f, pq = 0.0f;
    #pragma unroll
    for (int i = 0; i < 8; ++i) {
        const int d4 = i * 64 + lane;          // f32x4 index 0..511
        const f32x4 v  = __builtin_nontemporal_load(src + d4);
        const f32x4 qv = q4[d4];
        p2 += v.x * v.x + v.y * v.y + v.z * v.z + v.w * v.w;
        pq += qv.x * v.x + qv.y * v.y + qv.z * v.z + qv.w * v.w;
        ldsrow[d4 * 2 + 0] = __builtin_amdgcn_cvt_pkrtz(v.x, v.y);
        ldsrow[d4 * 2 + 1] = __builtin_amdgcn_cvt_pkrtz(v.z, v.w);
    }

    // ---- 64-lane butterfly reduce (p2, pq) ----
    #pragma unroll
    for (int m = 32; m >= 1; m >>= 1) {
        p2 += __shfl_xor(p2, m, 64);
        pq += __shfl_xor(pq, m, 64);
    }
    if (lane == 0) {
        const float ms  = p2 * (1.0f / ND) + 1.1920928955078125e-07f; // FLT_EPSILON
        s_scores[wave]  = pq * rsqrtf(ms) * 0.022097086912079608f;    // 1/sqrt(2048)
    }

    // ---- raw barrier: drain LDS writes only (no vmcnt(0) drain) ----
    asm volatile("s_waitcnt lgkmcnt(0)" ::: "memory");
    __builtin_amdgcn_s_barrier();

    // ---- Softmax over 16 sources, redundantly per thread ----
    float w[NSRC];
    float mx = -1e30f;
    #pragma unroll
    for (int s = 0; s < NSRC; ++s) { w[s] = s_scores[s]; mx = fmaxf(mx, w[s]); }
    float sum = 0.0f;
    #pragma unroll
    for (int s = 0; s < NSRC; ++s) { w[s] = __expf(w[s] - mx); sum += w[s]; }
    const float inv = 1.0f / sum;

    // ---- Mix: thread tid owns half2 slice at index tid (2-way alias = free) ----
    float ax = 0.0f, ay = 0.0f;
    #pragma unroll
    for (int s = 0; s < NSRC; ++s) {
        const half2_t h = lds[s * (ND / 2) + tid];
        ax += w[s] * (float)h.x;
        ay += w[s] * (float)h.y;
    }
    f32x2 r;
    r.x = ax * inv;
    r.y = ay * inv;
    __builtin_nontemporal_store(r, reinterpret_cast<f32x2*>(out + (size_t)bt * ND) + tid);
}

extern "C" void kernel_launch(void* const* d_in, const int* in_sizes, int n_in,
                              void* d_out, int out_size, void* d_ws, size_t ws_size,
                              hipStream_t stream) {
    const float* q    = (const float*)d_in[0];   // [D] fp32
    const float* bank = (const float*)d_in[1];   // [S,B,T,D] fp32
    float* out        = (float*)d_out;           // [B,T,D] fp32

    dim3 grid(NB * NT);
    dim3 block(1024);
    dar_fused_kernel<<<grid, block, 0, stream>>>(q, bank, out);
}

// Round 11
// 98.067 us; speedup vs baseline: 2.6164x; 1.0006x over previous
//
#include <hip/hip_runtime.h>

// DepthAttentionResidual: S=16 sources, B=4, T=1024, D=2048, fp32 in/out.
// R10 (98.1 us) + wave-group softmax:
//   - nontemporal bank loads / out stores (no L2/L3 evict churn)
//   - raw s_barrier with lgkmcnt(0)-only drain (no vmcnt(0) drain)
//   - softmax computed ONCE per 16-lane group (lane l owns source l&15):
//     1 expf/thread instead of 16, kills the 16-VGPR w[] array -> deeper
//     load pipelining under the 64-VGPR cap; weights broadcast via __shfl.

#define NSRC 16
#define NB   4
#define NT   1024
#define ND   2048

typedef __fp16 half2_t __attribute__((ext_vector_type(2)));
typedef float  f32x4   __attribute__((ext_vector_type(4)));
typedef float  f32x2   __attribute__((ext_vector_type(2)));

__global__ __launch_bounds__(1024, 8)
void dar_fused_kernel(const float* __restrict__ q,
                      const float* __restrict__ bank,
                      float* __restrict__ out) {
    __shared__ half2_t lds[NSRC * (ND / 2)];   // 64 KB
    __shared__ float s_scores[NSRC];

    const int bt   = blockIdx.x;       // b*NT + t
    const int tid  = threadIdx.x;      // 0..1023
    const int wave = tid >> 6;         // 0..15 == source index
    const int lane = tid & 63;

    // ---- Stage source `wave` into LDS (fp16); fuse sum(x^2), sum(q*x) ----
    const f32x4* src = reinterpret_cast<const f32x4*>(
        bank + ((size_t)wave * NB * NT + bt) * ND);
    const f32x4* q4  = reinterpret_cast<const f32x4*>(q);
    half2_t* ldsrow  = lds + wave * (ND / 2);

    float p2 = 0.0f, pq = 0.0f;
    #pragma unroll
    for (int i = 0; i < 8; ++i) {
        const int d4 = i * 64 + lane;          // f32x4 index 0..511
        const f32x4 v  = __builtin_nontemporal_load(src + d4);
        const f32x4 qv = q4[d4];
        p2 += v.x * v.x + v.y * v.y + v.z * v.z + v.w * v.w;
        pq += qv.x * v.x + qv.y * v.y + qv.z * v.z + qv.w * v.w;
        ldsrow[d4 * 2 + 0] = __builtin_amdgcn_cvt_pkrtz(v.x, v.y);
        ldsrow[d4 * 2 + 1] = __builtin_amdgcn_cvt_pkrtz(v.z, v.w);
    }

    // ---- 64-lane butterfly reduce (p2, pq) ----
    #pragma unroll
    for (int m = 32; m >= 1; m >>= 1) {
        p2 += __shfl_xor(p2, m, 64);
        pq += __shfl_xor(pq, m, 64);
    }
    if (lane == 0) {
        const float ms  = p2 * (1.0f / ND) + 1.1920928955078125e-07f; // FLT_EPSILON
        s_scores[wave]  = pq * rsqrtf(ms) * 0.022097086912079608f;    // 1/sqrt(2048)
    }

    // ---- raw barrier: drain LDS writes only (no vmcnt(0) drain) ----
    asm volatile("s_waitcnt lgkmcnt(0)" ::: "memory");
    __builtin_amdgcn_s_barrier();

    // ---- Group softmax: lane l owns source l&15; one expf per thread ----
    const float score = s_scores[lane & 15];   // same-address broadcast per bank
    float mx = score;
    #pragma unroll
    for (int m = 1; m <= 8; m <<= 1) mx = fmaxf(mx, __shfl_xor(mx, m, 64));
    const float es = __expf(score - mx);
    float sum = es;
    #pragma unroll
    for (int m = 1; m <= 8; m <<= 1) sum += __shfl_xor(sum, m, 64);
    const float esn = es / sum;                // normalized weight for source lane&15

    // ---- Mix: thread tid owns half2 slice `tid`; weights via __shfl ----
    float ax = 0.0f, ay = 0.0f;
    #pragma unroll
    for (int s = 0; s < NSRC; ++s) {
        const float ws = __shfl(esn, s, 64);
        const half2_t h = lds[s * (ND / 2) + tid];
        ax += ws * (float)h.x;
        ay += ws * (float)h.y;
    }
    f32x2 r;
    r.x = ax;
    r.y = ay;
    __builtin_nontemporal_store(r, reinterpret_cast<f32x2*>(out + (size_t)bt * ND) + tid);
}

extern "C" void kernel_launch(void* const* d_in, const int* in_sizes, int n_in,
                              void* d_out, int out_size, void* d_ws, size_t ws_size,
                              hipStream_t stream) {
    const float* q    = (const float*)d_in[0];   // [D] fp32
    const float* bank = (const float*)d_in[1];   // [S,B,T,D] fp32
    float* out        = (float*)d_out;           // [B,T,D] fp32

    dim3 grid(NB * NT);
    dim3 block(1024);
    dar_fused_kernel<<<grid, block, 0, stream>>>(q, bank, out);
}